// Round 3
// baseline (880.971 us; speedup 1.0000x reference)
//
#include <hip/hip_runtime.h>

#define NN 6144
#define BND (NN*16)

typedef short short8 __attribute__((ext_vector_type(8)));
typedef float f32x4 __attribute__((ext_vector_type(4)));

__device__ __forceinline__ short f2bf(float f) {
    unsigned u = __builtin_bit_cast(unsigned, f);
    u = (u + 0x7FFFu + ((u >> 16) & 1u)) >> 16;   // RNE to bf16
    return (short)u;
}
__device__ __forceinline__ float bf2f(unsigned short s) {
    unsigned u = ((unsigned)s) << 16;
    return __builtin_bit_cast(float, u);
}

// ---------------- prep: transpose X [8,6144,16] fp32 -> Xt [128][6144] bf16 ----------------
__global__ void __launch_bounds__(256) prep_kernel(
    const float* __restrict__ xin, unsigned short* __restrict__ Xt)
{
    __shared__ unsigned short ldsT[16 * 64];
    const int b  = blockIdx.y;
    const int m0 = blockIdx.x * 64;
    const int t  = threadIdx.x;
    const int ml = t >> 2, dq = t & 3;
    float4 v = *(const float4*)(xin + (size_t)b * BND + (size_t)(m0 + ml) * 16 + dq * 4);
    ldsT[(dq * 4 + 0) * 64 + ml] = (unsigned short)f2bf(v.x);
    ldsT[(dq * 4 + 1) * 64 + ml] = (unsigned short)f2bf(v.y);
    ldsT[(dq * 4 + 2) * 64 + ml] = (unsigned short)f2bf(v.z);
    ldsT[(dq * 4 + 3) * 64 + ml] = (unsigned short)f2bf(v.w);
    __syncthreads();
    if (t < 128) {
        int d = t >> 3, j = t & 7;
        short8 s = *(const short8*)&ldsT[d * 64 + j * 8];
        *(short8*)(Xt + (size_t)(b * 16 + d) * NN + m0 + j * 8) = s;
    }
}

// ---------------- main: Ypart[seg][k][n][c] (bf16) = partial (sup_k @ X) ----------------
// BARRIER-FREE streaming GEMM. LDS staging removed entirely:
//  - A (sup) is streamed ONCE, no reuse -> load MFMA fragments straight from global.
//    Lane L reads row n0+w*16+(L&15), k = ko+kc*32+(L>>4)*8 (+0..7): 2 x dwordx4,
//    16 rows x 256 B contiguous per wave-iter -> full lines consumed within the iter.
//  - B (Xt, 1.5 MB) is L2/L3-resident -> lane L reads short8 Xt[c][ko+kc*32+q*8]
//    directly (exactly the fragment the old LDS round-trip produced).
// Every wave is an independent stream: no __syncthreads, no vmcnt games; 16-20
// waves/CU of TLP keep HBM saturated (vs 4 synchronized block-streams before).
// Accumulation order identical to the verified round-0 kernel.
__global__ void __launch_bounds__(256, 3) gemm_kernel(
    const float* __restrict__ sup, const unsigned short* __restrict__ Xt,
    unsigned short* __restrict__ Yp)
{
    __shared__ float stgram[8192];    // 32 KB, epilogue staging only (private per wave)

    const int tid = threadIdx.x;
    const int w = tid >> 6, L = tid & 63, q = L >> 4, col = L & 15;
    const int n0  = blockIdx.x * 64;
    const int k   = blockIdx.y;
    const int seg = blockIdx.z;
    const int kbase = seg * 3072;

    const int r = w * 16 + col;       // this lane's A row within the 64-row tile
    const float* Arow = sup + (size_t)k * NN * NN + (size_t)(n0 + r) * NN + kbase + q * 8;
    const unsigned short* Bb = Xt + (size_t)col * NN + kbase + q * 8;

    f32x4 acc[8];
#pragma unroll
    for (int i = 0; i < 8; ++i) acc[i] = (f32x4)0.0f;

#pragma unroll 1
    for (int it = 0; it < 48; ++it) {
        const int ko = it * 64;
#pragma unroll
        for (int kc = 0; kc < 2; ++kc) {
            const float* ap = Arow + ko + kc * 32;
            float4 a0 = *(const float4*)ap;         // k = ko+kc*32+q*8 .. +3
            float4 a1 = *(const float4*)(ap + 4);   // k = .. +4 .. +7
            short8 bf[8];
#pragma unroll
            for (int cc = 0; cc < 8; ++cc)
                bf[cc] = *(const short8*)(Bb + (size_t)(cc * 16) * NN + ko + kc * 32);
            short8 af;
            af[0] = f2bf(a0.x); af[1] = f2bf(a0.y); af[2] = f2bf(a0.z); af[3] = f2bf(a0.w);
            af[4] = f2bf(a1.x); af[5] = f2bf(a1.y); af[6] = f2bf(a1.z); af[7] = f2bf(a1.w);
#pragma unroll
            for (int cc = 0; cc < 8; ++cc)
                acc[cc] = __builtin_amdgcn_mfma_f32_16x16x32_bf16(af, bf[cc], acc[cc], 0, 0, 0);
        }
    }

    // ---- epilogue: assemble in LDS (each wave its own private 8 KB region, no barrier
    // needed), then bf16 coalesced store ----
    float* stg = stgram + w * 2048;    // [16 rows][128 c]
#pragma unroll
    for (int cc = 0; cc < 8; ++cc)
#pragma unroll
        for (int rr = 0; rr < 4; ++rr)
            stg[(q * 4 + rr) * 128 + cc * 16 + col] = acc[cc][rr];  // C/D: col=lane&15, row=q*4+reg

    unsigned short* ypb = Yp + ((size_t)(seg * 3 + k) * NN + n0 + w * 16) * 128;
#pragma unroll
    for (int u = 0; u < 8; ++u) {
        int idx = u * 256 + L * 4;                // conflict-free float4 LDS read
        float4 v = *(const float4*)&stg[idx];
        unsigned h0 = (unsigned short)f2bf(v.x) | ((unsigned)(unsigned short)f2bf(v.y) << 16);
        unsigned h1 = (unsigned short)f2bf(v.z) | ((unsigned)(unsigned short)f2bf(v.w) << 16);
        uint2 pk; pk.x = h0; pk.y = h1;
        *(uint2*)(ypb + idx) = pk;                // rr = idx>>7, c = idx&127 folded linearly
    }
}

// ---------------- stage 2: out[b,n,o] = bias[o] + sum_{s,k,d} Yp*W' + identity ----------------
__global__ void __launch_bounds__(256) out_kernel(
    const unsigned short* __restrict__ Yp, const float* __restrict__ xin,
    const float* __restrict__ W, const float* __restrict__ bias, float* __restrict__ out)
{
    const int o   = threadIdx.x & 63;
    const int wid = blockIdx.x * 4 + (threadIdx.x >> 6);  // 2048 waves

    float wreg[48];                       // wreg[k*16+d] = W[o][d*3+k]
#pragma unroll
    for (int d = 0; d < 16; ++d)
#pragma unroll
        for (int kk = 0; kk < 3; ++kk)
            wreg[kk * 16 + d] = W[o * 48 + d * 3 + kk];
    float wsum[16];                       // identity term: sum_k wreg[k*16+d]
#pragma unroll
    for (int d = 0; d < 16; ++d) wsum[d] = wreg[d] + wreg[16 + d] + wreg[32 + d];
    const float bv = bias[o];

    for (int ii = 0; ii < 24; ++ii) {
        int p = wid * 24 + ii;            // p in [0, 49152)
        int b = p / NN;
        int n = p - b * NN;
        float acc = bv;
        const float* xp = xin + (size_t)b * BND + (size_t)n * 16;
#pragma unroll
        for (int d4 = 0; d4 < 4; ++d4) {
            float4 x4 = *(const float4*)(xp + d4 * 4);
            acc += x4.x * wsum[d4 * 4] + x4.y * wsum[d4 * 4 + 1]
                 + x4.z * wsum[d4 * 4 + 2] + x4.w * wsum[d4 * 4 + 3];
        }
#pragma unroll
        for (int s = 0; s < 2; ++s)
#pragma unroll
            for (int kk = 0; kk < 3; ++kk) {
                const unsigned short* yp = Yp + ((size_t)(s * 3 + kk) * NN + n) * 128 + b * 16;
                short8 y0 = *(const short8*)yp;
                short8 y1 = *(const short8*)(yp + 8);
#pragma unroll
                for (int j = 0; j < 8; ++j) {
                    acc += bf2f((unsigned short)y0[j]) * wreg[kk * 16 + j];
                    acc += bf2f((unsigned short)y1[j]) * wreg[kk * 16 + 8 + j];
                }
            }
        out[(size_t)p * 64 + o] = acc;
    }
}

extern "C" void kernel_launch(void* const* d_in, const int* in_sizes, int n_in,
                              void* d_out, int out_size, void* d_ws, size_t ws_size,
                              hipStream_t stream) {
    const float* xin  = (const float*)d_in[0];  // [8,6144,16]
    const float* sup  = (const float*)d_in[1];  // [3,6144,6144]
    const float* W    = (const float*)d_in[2];  // [64,48]
    const float* bias = (const float*)d_in[3];  // [64]
    float* out = (float*)d_out;                 // [8,6144,64]

    char* ws = (char*)d_ws;
    unsigned short* Xt = (unsigned short*)ws;        // 128*6144*2B = 1,572,864
    unsigned short* Yp = (unsigned short*)(ws + 1572864); // 2*3*6144*128*2B = 9,437,184

    prep_kernel<<<dim3(96, 8), 256, 0, stream>>>(xin, Xt);
    gemm_kernel<<<dim3(96, 3, 2), 256, 0, stream>>>(sup, Xt, Yp);
    out_kernel<<<512, 256, 0, stream>>>(Yp, xin, W, bias, out);
}

// Round 4
// 757.241 us; speedup vs baseline: 1.1634x; 1.1634x over previous
//
#include <hip/hip_runtime.h>

#define NN 6144
#define BND (NN*16)

typedef short short8 __attribute__((ext_vector_type(8)));
typedef float f32x4 __attribute__((ext_vector_type(4)));

__device__ __forceinline__ short f2bf(float f) {
    unsigned u = __builtin_bit_cast(unsigned, f);
    u = (u + 0x7FFFu + ((u >> 16) & 1u)) >> 16;   // RNE to bf16
    return (short)u;
}
__device__ __forceinline__ float bf2f(unsigned short s) {
    unsigned u = ((unsigned)s) << 16;
    return __builtin_bit_cast(float, u);
}

// ---------------- prep: transpose X [8,6144,16] fp32 -> Xt [128][6144] bf16 ----------------
__global__ void __launch_bounds__(256) prep_kernel(
    const float* __restrict__ xin, unsigned short* __restrict__ Xt)
{
    __shared__ unsigned short ldsT[16 * 64];
    const int b  = blockIdx.y;
    const int m0 = blockIdx.x * 64;
    const int t  = threadIdx.x;
    const int ml = t >> 2, dq = t & 3;
    float4 v = *(const float4*)(xin + (size_t)b * BND + (size_t)(m0 + ml) * 16 + dq * 4);
    ldsT[(dq * 4 + 0) * 64 + ml] = (unsigned short)f2bf(v.x);
    ldsT[(dq * 4 + 1) * 64 + ml] = (unsigned short)f2bf(v.y);
    ldsT[(dq * 4 + 2) * 64 + ml] = (unsigned short)f2bf(v.z);
    ldsT[(dq * 4 + 3) * 64 + ml] = (unsigned short)f2bf(v.w);
    __syncthreads();
    if (t < 128) {
        int d = t >> 3, j = t & 7;
        short8 s = *(const short8*)&ldsT[d * 64 + j * 8];
        *(short8*)(Xt + (size_t)(b * 16 + d) * NN + m0 + j * 8) = s;
    }
}

// ---------------- main: Ypart[seg][k][n][c] (bf16) = partial (sup_k @ X) ----------------
// Round-0 verified structure (global_load_lds staging, 2 barriers/K-step) — the only
// schedule that measured 708.5; rounds 1-3 proved restructuring the sync loses.
// One change: K-split 4 (seg dim 2->4) => 1152 blocks (4.5/CU vs 2.25). Finer work
// granularity lets dynamic dispatch balance CUs (old static split stranded 33% at the
// tail) and keeps 4 independent staging streams per CU so HBM never idles while any
// one block sits in its drain+compute phase.
__global__ void __launch_bounds__(256, 4) gemm_kernel(
    const float* __restrict__ sup, const unsigned short* __restrict__ Xt,
    unsigned short* __restrict__ Yp)
{
    __shared__ float ldsram[8192];                       // 32 KB
    float* ldsA = ldsram;                                // 16 KB: 64r x 16 chunks(16B) swizzled
    unsigned short* ldsB = (unsigned short*)(ldsram + 4096); // 16 KB: 128c x 8 chunks swizzled

    const int tid = threadIdx.x;
    const int w = tid >> 6, L = tid & 63, q = L >> 4, col = L & 15;
    const int n0  = blockIdx.x * 64;
    const int k   = blockIdx.y;
    const int seg = blockIdx.z;
    const float* Ab = sup + (size_t)k * NN * NN;

    f32x4 acc[8];
#pragma unroll
    for (int i = 0; i < 8; ++i) acc[i] = (f32x4)0.0f;

    for (int it = 0; it < 24; ++it) {
        const int k0 = seg * 1536 + it * 64;
        // ---- stage A: 16 KB fp32, coalesced, src-XOR-swizzled ----
#pragma unroll
        for (int i = 0; i < 4; ++i) {
            int p = i * 256 + tid;
            int r = p >> 4, cs = p & 15;
            int cch = cs ^ (r & 7);
            const float* src = Ab + (size_t)(n0 + r) * NN + k0 + cch * 4;
            __builtin_amdgcn_global_load_lds(
                (const __attribute__((address_space(1))) unsigned int*)src,
                (__attribute__((address_space(3))) unsigned int*)((char*)ldsA + p * 16), 16, 0, 0);
        }
        // ---- stage B: 16 KB bf16 from Xt (L2), coalesced, src-XOR-swizzled ----
#pragma unroll
        for (int i = 0; i < 4; ++i) {
            int p = i * 256 + tid;
            int c = p >> 3, hs = p & 7;
            int h = hs ^ (c & 7);
            const unsigned short* src = Xt + (size_t)c * NN + k0 + h * 8;
            __builtin_amdgcn_global_load_lds(
                (const __attribute__((address_space(1))) unsigned int*)src,
                (__attribute__((address_space(3))) unsigned int*)((char*)ldsB + p * 16), 16, 0, 0);
        }
        __syncthreads();   // vmcnt(0) drain: tiles ready

        const int r = w * 16 + col;   // wave w owns rows [w*16, w*16+16)
#pragma unroll
        for (int kc = 0; kc < 2; ++kc) {
            int c0 = kc * 8 + q * 2;
            float4 a0 = *(const float4*)&ldsA[(r * 16 + ((c0    ) ^ (r & 7))) * 4];
            float4 a1 = *(const float4*)&ldsA[(r * 16 + ((c0 + 1) ^ (r & 7))) * 4];
            short8 af;
            af[0] = f2bf(a0.x); af[1] = f2bf(a0.y); af[2] = f2bf(a0.z); af[3] = f2bf(a0.w);
            af[4] = f2bf(a1.x); af[5] = f2bf(a1.y); af[6] = f2bf(a1.z); af[7] = f2bf(a1.w);
#pragma unroll
            for (int cc = 0; cc < 8; ++cc) {
                int c = cc * 16 + col;
                short8 bf = *(const short8*)&ldsB[(c * 8 + ((kc * 4 + q) ^ (c & 7))) * 8];
                acc[cc] = __builtin_amdgcn_mfma_f32_16x16x32_bf16(af, bf, acc[cc], 0, 0, 0);
            }
        }
        __syncthreads();   // protect LDS before next staging
    }

    // ---- epilogue: assemble in LDS (each wave its own 8 KB region), bf16 coalesced store ----
    float* stg = ldsram + w * 2048;    // [16 rows][128 c]
#pragma unroll
    for (int cc = 0; cc < 8; ++cc)
#pragma unroll
        for (int rr = 0; rr < 4; ++rr)
            stg[(q * 4 + rr) * 128 + cc * 16 + col] = acc[cc][rr];  // C/D: col=lane&15, row=q*4+reg

    unsigned short* ypb = Yp + ((size_t)(seg * 3 + k) * NN + n0 + w * 16) * 128;
#pragma unroll
    for (int u = 0; u < 8; ++u) {
        int idx = u * 256 + L * 4;                // conflict-free float4 LDS read
        float4 v = *(const float4*)&stg[idx];
        unsigned h0 = (unsigned short)f2bf(v.x) | ((unsigned)(unsigned short)f2bf(v.y) << 16);
        unsigned h1 = (unsigned short)f2bf(v.z) | ((unsigned)(unsigned short)f2bf(v.w) << 16);
        uint2 pk; pk.x = h0; pk.y = h1;
        *(uint2*)(ypb + idx) = pk;                // rr = idx>>7, c = idx&127 folded linearly
    }
}

// ---------------- stage 2: out[b,n,o] = bias[o] + sum_{s,k,d} Yp*W' + identity ----------------
__global__ void __launch_bounds__(256) out_kernel(
    const unsigned short* __restrict__ Yp, const float* __restrict__ xin,
    const float* __restrict__ W, const float* __restrict__ bias, float* __restrict__ out)
{
    const int o   = threadIdx.x & 63;
    const int wid = blockIdx.x * 4 + (threadIdx.x >> 6);  // 2048 waves

    float wreg[48];                       // wreg[k*16+d] = W[o][d*3+k]
#pragma unroll
    for (int d = 0; d < 16; ++d)
#pragma unroll
        for (int kk = 0; kk < 3; ++kk)
            wreg[kk * 16 + d] = W[o * 48 + d * 3 + kk];
    float wsum[16];                       // identity term: sum_k wreg[k*16+d]
#pragma unroll
    for (int d = 0; d < 16; ++d) wsum[d] = wreg[d] + wreg[16 + d] + wreg[32 + d];
    const float bv = bias[o];

    for (int ii = 0; ii < 24; ++ii) {
        int p = wid * 24 + ii;            // p in [0, 49152)
        int b = p / NN;
        int n = p - b * NN;
        float acc = bv;
        const float* xp = xin + (size_t)b * BND + (size_t)n * 16;
#pragma unroll
        for (int d4 = 0; d4 < 4; ++d4) {
            float4 x4 = *(const float4*)(xp + d4 * 4);
            acc += x4.x * wsum[d4 * 4] + x4.y * wsum[d4 * 4 + 1]
                 + x4.z * wsum[d4 * 4 + 2] + x4.w * wsum[d4 * 4 + 3];
        }
#pragma unroll
        for (int s = 0; s < 4; ++s)
#pragma unroll
            for (int kk = 0; kk < 3; ++kk) {
                const unsigned short* yp = Yp + ((size_t)(s * 3 + kk) * NN + n) * 128 + b * 16;
                short8 y0 = *(const short8*)yp;
                short8 y1 = *(const short8*)(yp + 8);
#pragma unroll
                for (int j = 0; j < 8; ++j) {
                    acc += bf2f((unsigned short)y0[j]) * wreg[kk * 16 + j];
                    acc += bf2f((unsigned short)y1[j]) * wreg[kk * 16 + 8 + j];
                }
            }
        out[(size_t)p * 64 + o] = acc;
    }
}

extern "C" void kernel_launch(void* const* d_in, const int* in_sizes, int n_in,
                              void* d_out, int out_size, void* d_ws, size_t ws_size,
                              hipStream_t stream) {
    const float* xin  = (const float*)d_in[0];  // [8,6144,16]
    const float* sup  = (const float*)d_in[1];  // [3,6144,6144]
    const float* W    = (const float*)d_in[2];  // [64,48]
    const float* bias = (const float*)d_in[3];  // [64]
    float* out = (float*)d_out;                 // [8,6144,64]

    char* ws = (char*)d_ws;
    unsigned short* Xt = (unsigned short*)ws;        // 128*6144*2B = 1,572,864
    unsigned short* Yp = (unsigned short*)(ws + 1572864); // 4*3*6144*128*2B = 18,874,368

    prep_kernel<<<dim3(96, 8), 256, 0, stream>>>(xin, Xt);
    gemm_kernel<<<dim3(96, 3, 4), 256, 0, stream>>>(sup, Xt, Yp);
    out_kernel<<<512, 256, 0, stream>>>(Yp, xin, W, bias, out);
}

// Round 5
// 710.740 us; speedup vs baseline: 1.2395x; 1.0654x over previous
//
#include <hip/hip_runtime.h>

#define NN 6144
#define BND (NN*16)

typedef short short8 __attribute__((ext_vector_type(8)));
typedef float f32x4 __attribute__((ext_vector_type(4)));

__device__ __forceinline__ short f2bf(float f) {
    unsigned u = __builtin_bit_cast(unsigned, f);
    u = (u + 0x7FFFu + ((u >> 16) & 1u)) >> 16;   // RNE to bf16
    return (short)u;
}
__device__ __forceinline__ float bf2f(unsigned short s) {
    unsigned u = ((unsigned)s) << 16;
    return __builtin_bit_cast(float, u);
}

// ---------------- prep: transpose X [8,6144,16] fp32 -> Xt [128][6144] bf16 ----------------
__global__ void __launch_bounds__(256) prep_kernel(
    const float* __restrict__ xin, unsigned short* __restrict__ Xt)
{
    __shared__ unsigned short ldsT[16 * 64];
    const int b  = blockIdx.y;
    const int m0 = blockIdx.x * 64;
    const int t  = threadIdx.x;
    const int ml = t >> 2, dq = t & 3;
    float4 v = *(const float4*)(xin + (size_t)b * BND + (size_t)(m0 + ml) * 16 + dq * 4);
    ldsT[(dq * 4 + 0) * 64 + ml] = (unsigned short)f2bf(v.x);
    ldsT[(dq * 4 + 1) * 64 + ml] = (unsigned short)f2bf(v.y);
    ldsT[(dq * 4 + 2) * 64 + ml] = (unsigned short)f2bf(v.z);
    ldsT[(dq * 4 + 3) * 64 + ml] = (unsigned short)f2bf(v.w);
    __syncthreads();
    if (t < 128) {
        int d = t >> 3, j = t & 7;
        short8 s = *(const short8*)&ldsT[d * 64 + j * 8];
        *(short8*)(Xt + (size_t)(b * 16 + d) * NN + m0 + j * 8) = s;
    }
}

// ---------------- main: Ypart[seg][k][n][c] (bf16) = partial (sup_k @ X) ----------------
// ROUND-0 VERIFIED STRUCTURE (708.5 us) — restored verbatim. The measured bracket:
//   dbuf+vmcnt0 (743), 3-ring+vmcnt4 (720), no-LDS streaming (881), K-split-4 (757)
// all lose to this 2-barrier-per-K-step schedule; cross-block overlap (2-3 resident
// block-streams/CU) already covers the staging drain, and every added mechanism
// (deeper pipeline, more blocks, no staging) costs more than it recovers.
__global__ void __launch_bounds__(256, 4) gemm_kernel(
    const float* __restrict__ sup, const unsigned short* __restrict__ Xt,
    unsigned short* __restrict__ Yp)
{
    __shared__ float ldsram[8192];                       // 32 KB
    float* ldsA = ldsram;                                // 16 KB: 64r x 16 chunks(16B) swizzled
    unsigned short* ldsB = (unsigned short*)(ldsram + 4096); // 16 KB: 128c x 8 chunks swizzled

    const int tid = threadIdx.x;
    const int w = tid >> 6, L = tid & 63, q = L >> 4, col = L & 15;
    const int n0  = blockIdx.x * 64;
    const int k   = blockIdx.y;
    const int seg = blockIdx.z;
    const float* Ab = sup + (size_t)k * NN * NN;

    f32x4 acc[8];
#pragma unroll
    for (int i = 0; i < 8; ++i) acc[i] = (f32x4)0.0f;

    for (int it = 0; it < 48; ++it) {
        const int k0 = seg * 3072 + it * 64;
        // ---- stage A: 16 KB fp32, coalesced, src-XOR-swizzled ----
#pragma unroll
        for (int i = 0; i < 4; ++i) {
            int p = i * 256 + tid;
            int r = p >> 4, cs = p & 15;
            int cch = cs ^ (r & 7);
            const float* src = Ab + (size_t)(n0 + r) * NN + k0 + cch * 4;
            __builtin_amdgcn_global_load_lds(
                (const __attribute__((address_space(1))) unsigned int*)src,
                (__attribute__((address_space(3))) unsigned int*)((char*)ldsA + p * 16), 16, 0, 0);
        }
        // ---- stage B: 16 KB bf16 from Xt (L2), coalesced, src-XOR-swizzled ----
#pragma unroll
        for (int i = 0; i < 4; ++i) {
            int p = i * 256 + tid;
            int c = p >> 3, hs = p & 7;
            int h = hs ^ (c & 7);
            const unsigned short* src = Xt + (size_t)c * NN + k0 + h * 8;
            __builtin_amdgcn_global_load_lds(
                (const __attribute__((address_space(1))) unsigned int*)src,
                (__attribute__((address_space(3))) unsigned int*)((char*)ldsB + p * 16), 16, 0, 0);
        }
        __syncthreads();   // vmcnt(0) drain: tiles ready

        const int r = w * 16 + col;   // wave w owns rows [w*16, w*16+16)
#pragma unroll
        for (int kc = 0; kc < 2; ++kc) {
            int c0 = kc * 8 + q * 2;
            float4 a0 = *(const float4*)&ldsA[(r * 16 + ((c0    ) ^ (r & 7))) * 4];
            float4 a1 = *(const float4*)&ldsA[(r * 16 + ((c0 + 1) ^ (r & 7))) * 4];
            short8 af;
            af[0] = f2bf(a0.x); af[1] = f2bf(a0.y); af[2] = f2bf(a0.z); af[3] = f2bf(a0.w);
            af[4] = f2bf(a1.x); af[5] = f2bf(a1.y); af[6] = f2bf(a1.z); af[7] = f2bf(a1.w);
#pragma unroll
            for (int cc = 0; cc < 8; ++cc) {
                int c = cc * 16 + col;
                short8 bf = *(const short8*)&ldsB[(c * 8 + ((kc * 4 + q) ^ (c & 7))) * 8];
                acc[cc] = __builtin_amdgcn_mfma_f32_16x16x32_bf16(af, bf, acc[cc], 0, 0, 0);
            }
        }
        __syncthreads();   // protect LDS before next staging
    }

    // ---- epilogue: assemble in LDS (each wave its own 8 KB region), bf16 coalesced store ----
    float* stg = ldsram + w * 2048;    // [16 rows][128 c]
#pragma unroll
    for (int cc = 0; cc < 8; ++cc)
#pragma unroll
        for (int rr = 0; rr < 4; ++rr)
            stg[(q * 4 + rr) * 128 + cc * 16 + col] = acc[cc][rr];  // C/D: col=lane&15, row=q*4+reg

    unsigned short* ypb = Yp + ((size_t)(seg * 3 + k) * NN + n0 + w * 16) * 128;
#pragma unroll
    for (int u = 0; u < 8; ++u) {
        int idx = u * 256 + L * 4;                // conflict-free float4 LDS read
        float4 v = *(const float4*)&stg[idx];
        unsigned h0 = (unsigned short)f2bf(v.x) | ((unsigned)(unsigned short)f2bf(v.y) << 16);
        unsigned h1 = (unsigned short)f2bf(v.z) | ((unsigned)(unsigned short)f2bf(v.w) << 16);
        uint2 pk; pk.x = h0; pk.y = h1;
        *(uint2*)(ypb + idx) = pk;                // rr = idx>>7, c = idx&127 folded linearly
    }
}

// ---------------- stage 2: out[b,n,o] = bias[o] + sum_{s,k,d} Yp*W' + identity ----------------
__global__ void __launch_bounds__(256) out_kernel(
    const unsigned short* __restrict__ Yp, const float* __restrict__ xin,
    const float* __restrict__ W, const float* __restrict__ bias, float* __restrict__ out)
{
    const int o   = threadIdx.x & 63;
    const int wid = blockIdx.x * 4 + (threadIdx.x >> 6);  // 2048 waves

    float wreg[48];                       // wreg[k*16+d] = W[o][d*3+k]
#pragma unroll
    for (int d = 0; d < 16; ++d)
#pragma unroll
        for (int kk = 0; kk < 3; ++kk)
            wreg[kk * 16 + d] = W[o * 48 + d * 3 + kk];
    float wsum[16];                       // identity term: sum_k wreg[k*16+d]
#pragma unroll
    for (int d = 0; d < 16; ++d) wsum[d] = wreg[d] + wreg[16 + d] + wreg[32 + d];
    const float bv = bias[o];

    for (int ii = 0; ii < 24; ++ii) {
        int p = wid * 24 + ii;            // p in [0, 49152)
        int b = p / NN;
        int n = p - b * NN;
        float acc = bv;
        const float* xp = xin + (size_t)b * BND + (size_t)n * 16;
#pragma unroll
        for (int d4 = 0; d4 < 4; ++d4) {
            float4 x4 = *(const float4*)(xp + d4 * 4);
            acc += x4.x * wsum[d4 * 4] + x4.y * wsum[d4 * 4 + 1]
                 + x4.z * wsum[d4 * 4 + 2] + x4.w * wsum[d4 * 4 + 3];
        }
#pragma unroll
        for (int s = 0; s < 2; ++s)
#pragma unroll
            for (int kk = 0; kk < 3; ++kk) {
                const unsigned short* yp = Yp + ((size_t)(s * 3 + kk) * NN + n) * 128 + b * 16;
                short8 y0 = *(const short8*)yp;
                short8 y1 = *(const short8*)(yp + 8);
#pragma unroll
                for (int j = 0; j < 8; ++j) {
                    acc += bf2f((unsigned short)y0[j]) * wreg[kk * 16 + j];
                    acc += bf2f((unsigned short)y1[j]) * wreg[kk * 16 + 8 + j];
                }
            }
        out[(size_t)p * 64 + o] = acc;
    }
}

extern "C" void kernel_launch(void* const* d_in, const int* in_sizes, int n_in,
                              void* d_out, int out_size, void* d_ws, size_t ws_size,
                              hipStream_t stream) {
    const float* xin  = (const float*)d_in[0];  // [8,6144,16]
    const float* sup  = (const float*)d_in[1];  // [3,6144,6144]
    const float* W    = (const float*)d_in[2];  // [64,48]
    const float* bias = (const float*)d_in[3];  // [64]
    float* out = (float*)d_out;                 // [8,6144,64]

    char* ws = (char*)d_ws;
    unsigned short* Xt = (unsigned short*)ws;        // 128*6144*2B = 1,572,864
    unsigned short* Yp = (unsigned short*)(ws + 1572864); // 2*3*6144*128*2B = 9,437,184

    prep_kernel<<<dim3(96, 8), 256, 0, stream>>>(xin, Xt);
    gemm_kernel<<<dim3(96, 3, 2), 256, 0, stream>>>(sup, Xt, Yp);
    out_kernel<<<512, 256, 0, stream>>>(Yp, xin, W, bias, out);
}